// Round 2
// baseline (268.994 us; speedup 1.0000x reference)
//
#include <hip/hip_runtime.h>
#include <math.h>

#define HID 128
typedef unsigned int uint;
typedef unsigned short u16;
typedef unsigned char u8;
typedef __attribute__((ext_vector_type(8))) __bf16 bf16x8;
typedef __attribute__((ext_vector_type(4))) float f32x4;
typedef __attribute__((ext_vector_type(2))) float f32x2;

// ---------------- bf16 helpers (RNE) ----------------

__device__ __forceinline__ uint pack_bf2(float x, float y) {
    union { float f; uint u; } a, b;
    a.f = x; b.f = y;
    uint lo = (a.u + 0x7fffu + ((a.u >> 16) & 1u)) >> 16;
    uint hi = (b.u + 0x7fffu + ((b.u >> 16) & 1u)) & 0xffff0000u;
    return lo | hi;
}

__device__ __forceinline__ unsigned short bf16r(float x) {
    union { float f; uint u; } a; a.f = x;
    return (unsigned short)((a.u + 0x7fffu + ((a.u >> 16) & 1u)) >> 16);
}

__device__ __forceinline__ f32x2 bf2f(uint v) {
    union { uint u[2]; f32x2 f; } r;
    r.u[0] = v << 16;
    r.u[1] = v & 0xffff0000u;
    return r.f;
}

__device__ __forceinline__ f32x2 mk2(float s) { f32x2 r; r.x = s; r.y = s; return r; }
__device__ __forceinline__ f32x2 max2z(f32x2 a) {
    f32x2 r; r.x = fmaxf(a.x, 0.f); r.y = fmaxf(a.y, 0.f); return r;
}

// DPP-based add of a lane-permuted copy: single VALU op chain, no LDS pipe.
template<int CTRL>
__device__ __forceinline__ float dpp_add(float x) {
    union { float f; int i; } u, r;
    u.f = x;
    r.i = __builtin_amdgcn_update_dpp(0, u.i, CTRL, 0xf, 0xf, true);
    return x + r.f;
}

// packed fp32 math (CDNA3+ V_PK_*_F32), forced via inline asm
__device__ __forceinline__ f32x2 pk_add2(f32x2 a, f32x2 b) {
    f32x2 d;
    asm("v_pk_add_f32 %0, %1, %2" : "=v"(d) : "v"(a), "v"(b));
    return d;
}
__device__ __forceinline__ f32x2 pk_fma2(f32x2 a, f32x2 b, f32x2 c) {
    f32x2 d;
    asm("v_pk_fma_f32 %0, %1, %2, %3" : "=v"(d) : "v"(a), "v"(b), "v"(c));
    return d;
}

// ---------------- setup kernels ----------------

// composite weights: Wc = W2 @ [Wm1_top | Wm1_mid] (128 x 256), bf16 MFMA frag order
// brow = b2 @ [Wm1_top | Wm1_mid] + [bm1 | 0]  (256).  K-split x4 + DPP quad-reduce.
__global__ void prep_kernel(const float* __restrict__ W2, const float* __restrict__ Wm1,
                            const float* __restrict__ b2, const float* __restrict__ bm1,
                            uint* __restrict__ fWc, float* __restrict__ brow) {
    int t0 = blockIdx.x * blockDim.x + threadIdx.x;
    if (t0 < 65536) {       // 16384 outputs * 4 K-slices
        int ks = t0 & 3;
        int i = t0 >> 2;
        int p = i & 3, lane = (i >> 2) & 63, kk = (i >> 8) & 3, ct = i >> 10;
        int k = kk * 32 + (lane >> 4) * 8 + p * 2;
        int n2 = ct * 16 + (lane & 15);
        const float* wmc = (n2 < 128) ? (Wm1 + n2) : (Wm1 + 128 * HID + (n2 - 128));
        const float* w2r0 = W2 + (size_t)k * HID + ks * 32;
        const float* w2r1 = w2r0 + HID;
        const float* wm = wmc + (size_t)(ks * 32) * HID;
        float d0 = 0.f, d1 = 0.f;
        #pragma unroll 8
        for (int j = 0; j < 32; ++j) {
            float w = wm[(size_t)j * HID];
            d0 += w2r0[j] * w;
            d1 += w2r1[j] * w;
        }
        d0 = dpp_add<0xB1>(d0); d0 = dpp_add<0x4E>(d0);
        d1 = dpp_add<0xB1>(d1); d1 = dpp_add<0x4E>(d1);
        if (ks == 0) fWc[i] = pack_bf2(d0, d1);
    } else if (t0 < 65536 + 1024) {
        int r = t0 - 65536;
        int ks = r & 3;
        int i = r >> 2;
        const float* wmc = (i < 128) ? (Wm1 + i) : (Wm1 + 128 * HID + (i - 128));
        float d = 0.f;
        for (int j = ks * 32; j < ks * 32 + 32; ++j) d += b2[j] * wmc[(size_t)j * HID];
        d = dpp_add<0xB1>(d); d = dpp_add<0x4E>(d);
        if (ks == 0) brow[i] = d + ((i < 128) ? bm1[i] : 0.f);
    }
}

// histogram + within-bucket rank (atomic return value)
__global__ void hist_rank(const int* __restrict__ dst, int* __restrict__ cnt,
                          int* __restrict__ rank, int E) {
    int e = blockIdx.x * blockDim.x + threadIdx.x;
    if (e < E) rank[e] = atomicAdd(&cnt[dst[e]], 1);
}

__global__ void scan1(const int* __restrict__ cnt, int* __restrict__ excl,
                      int* __restrict__ bsum, int N) {
    __shared__ int sh[256];
    int tid = threadIdx.x;
    int gid = blockIdx.x * 256 + tid;
    int v = (gid < N) ? cnt[gid] : 0;
    sh[tid] = v;
    __syncthreads();
    for (int o = 1; o < 256; o <<= 1) {
        int t = (tid >= o) ? sh[tid - o] : 0;
        __syncthreads();
        sh[tid] += t;
        __syncthreads();
    }
    if (gid < N) excl[gid] = sh[tid] - v;
    if (tid == 255) bsum[blockIdx.x] = sh[255];
}

// finalize rowptr/dis + write xps[n] = bf16(dis[n]*x[n]) packed (5 dims + pad)
__global__ void scan3x(const int* __restrict__ cnt, int* __restrict__ rowptr,
                       const int* __restrict__ bsum,
                       float* __restrict__ dis, const float* __restrict__ x,
                       uint4* __restrict__ xps, int N, int E, int NB) {
    __shared__ int sh[256];
    __shared__ int ex[256];
    int tid = threadIdx.x;
    int v = (tid < NB) ? bsum[tid] : 0;
    sh[tid] = v;
    __syncthreads();
    for (int o = 1; o < 256; o <<= 1) {
        int t = (tid >= o) ? sh[tid - o] : 0;
        __syncthreads();
        sh[tid] += t;
        __syncthreads();
    }
    ex[tid] = sh[tid] - v;
    __syncthreads();
    int gid = blockIdx.x * 256 + tid;
    if (gid < N) {
        rowptr[gid] = rowptr[gid] + ex[blockIdx.x];
        float dn = rsqrtf((float)cnt[gid] + 1.0f);   // deg incl. self-loop
        dis[gid] = dn;
        const float* xr = x + (size_t)gid * 5;
        uint4 pk;
        pk.x = pack_bf2(dn * xr[0], dn * xr[1]);
        pk.y = pack_bf2(dn * xr[2], dn * xr[3]);
        pk.z = pack_bf2(dn * xr[4], 0.f);
        pk.w = 0u;
        xps[gid] = pk;
    }
    if (gid == N) rowptr[N] = E;
}

// atomic-free scatter: pos = rowptr[dst] + rank; csr2[pos] = (src|dst<<16, eid)
// also reorders ea into dst-sorted ear[] (so edge_mlp reads it coalesced)
__global__ void scatter2(const int* __restrict__ src, const int* __restrict__ dst,
                         const int* __restrict__ rowptr, const int* __restrict__ rank,
                         const float4* __restrict__ ea,
                         uint2* __restrict__ csr2, float4* __restrict__ ear,
                         int use_ear, int E) {
    int e = blockIdx.x * blockDim.x + threadIdx.x;
    if (e < E) {
        int d = dst[e];
        int pos = rowptr[d] + rank[e];
        csr2[pos] = make_uint2((uint)src[e] | ((uint)d << 16), (uint)e);
        if (use_ear) ear[pos] = ea[e];
    }
}

// ---------------- fused layer-1: hs1 = dis * relu( (S·x) @ W1 + b1 ) ----------------
// 4 lanes per node (quad): edge gathers split 4-way + DPP quad-reduce.
__launch_bounds__(256)
__global__ void layer1_kernel(const uint4* __restrict__ xps, const uint2* __restrict__ csr2,
                              const int* __restrict__ rowptr, const float* __restrict__ dis,
                              const float* __restrict__ W1, const float* __restrict__ b1,
                              uint* __restrict__ hs1, int N) {
    __shared__ float sW[5 * HID];
    __shared__ float sb[HID];
    int tid = threadIdx.x;
    for (int i = tid; i < 5 * HID; i += 256) sW[i] = W1[i];
    for (int i = tid; i < HID; i += 256) sb[i] = b1[i];
    __syncthreads();

    int sub = tid & 3;
    int n = blockIdx.x * 64 + (tid >> 2);
    if (n >= N) return;
    int beg = rowptr[n], end = rowptr[n + 1];
    float a0 = 0.f, a1 = 0.f, a2 = 0.f, a3 = 0.f, a4 = 0.f;
    for (int i = beg + sub; i < end; i += 4) {
        uint s = csr2[i].x & 0xffffu;
        uint4 v = xps[s];
        f32x2 v01 = bf2f(v.x), v23 = bf2f(v.y), v4 = bf2f(v.z);
        a0 += v01.x; a1 += v01.y; a2 += v23.x; a3 += v23.y; a4 += v4.x;
    }
    a0 = dpp_add<0xB1>(a0); a0 = dpp_add<0x4E>(a0);
    a1 = dpp_add<0xB1>(a1); a1 = dpp_add<0x4E>(a1);
    a2 = dpp_add<0xB1>(a2); a2 = dpp_add<0x4E>(a2);
    a3 = dpp_add<0xB1>(a3); a3 = dpp_add<0x4E>(a3);
    a4 = dpp_add<0xB1>(a4); a4 = dpp_add<0x4E>(a4);
    {
        uint4 v = xps[n];   // self-loop term
        f32x2 v01 = bf2f(v.x), v23 = bf2f(v.y), v4 = bf2f(v.z);
        a0 += v01.x; a1 += v01.y; a2 += v23.x; a3 += v23.y; a4 += v4.x;
    }
    float dn = dis[n];
    a0 *= dn; a1 *= dn; a2 *= dn; a3 *= dn; a4 *= dn;   // sx row

    uint* op = hs1 + (size_t)n * 64;
    #pragma unroll
    for (int p = 0; p < 16; ++p) {
        int q = p * 4 + sub;
        int j = q * 2;
        float t0 = sb[j]     + a0 * sW[j]     + a1 * sW[HID + j]     + a2 * sW[2*HID + j]
                             + a3 * sW[3*HID + j] + a4 * sW[4*HID + j];
        float t1 = sb[j + 1] + a0 * sW[j + 1] + a1 * sW[HID + j + 1] + a2 * sW[2*HID + j + 1]
                             + a3 * sW[3*HID + j + 1] + a4 * sW[4*HID + j + 1];
        op[q] = pack_bf2(fmaxf(t0, 0.f) * dn, fmaxf(t1, 0.f) * dn);
    }
}

// ---------------- fused aggregate + GEMM (MFMA segment-sum) ----------------
// block = 4 waves = 16 nodes.  Per 32-edge chunk: stage gathered hs1 rows to LDS
// (coalesced, XOR-swizzled), then one indicator-MFMA per wave per col-tile:
//   D[16 nodes][16 cols] += Ind[16x32] @ Rows[32x16].
// Self-loops injected as a final 16-slot chunk.  Phase 2 (x Wc + brow) unchanged.
__launch_bounds__(256)
__global__ void agg_gemm(const uint4* __restrict__ hs1, const uint2* __restrict__ csr2,
                         const int* __restrict__ rowptr, const float* __restrict__ dis,
                         const uint4* __restrict__ Bf, const float* __restrict__ brow,
                         unsigned short* __restrict__ out, int N) {
    __shared__ u16 Bs[32 * 128];          // staged slot rows (bf16), 8 KB, swizzled
    __shared__ u16 gtu[16 * 128];         // aggregated g tile (bf16), 4 KB
    __shared__ u16 ssrc[32];
    __shared__ __align__(8) u8 sown[32];

    int tid = threadIdx.x;
    int wave = tid >> 6, lane = tid & 63;
    int gl = lane & 15, q = lane >> 4;
    int nb = blockIdx.x * 16;

    int hi = nb + 16; if (hi > N) hi = N;
    int e0 = rowptr[nb];
    int e1 = rowptr[hi];
    int nchunk = (e1 - e0 + 31) >> 5;     // edge chunks; chunk nchunk = self-loops

    f32x4 acc0 = {0.f, 0.f, 0.f, 0.f};
    f32x4 acc1 = {0.f, 0.f, 0.f, 0.f};
    int colb0 = (wave * 2) * 16 + gl;
    int colb1 = (wave * 2 + 1) * 16 + gl;

    for (int c = 0; c <= nchunk; ++c) {
        // slot metadata: src id + owner node (from csr2 dst field)
        if (tid < 32) {
            uint own = 0xffu, sid = (uint)nb;
            if (c < nchunk) {
                int i = e0 + c * 32 + tid;
                if (i < e1) {
                    uint cx = csr2[i].x;
                    sid = cx & 0xffffu;
                    own = (cx >> 16) - (uint)nb;
                }
            } else if (tid < 16 && nb + tid < N) {
                own = (uint)tid; sid = (uint)(nb + tid);
            }
            ssrc[tid] = (u16)sid;
            sown[tid] = (u8)own;
        }
        __syncthreads();
        // stage 32 rows x 256B, coalesced; byte-swizzle bits 4-5 by slot>>3
        #pragma unroll
        for (int p = 0; p < 2; ++p) {
            int idx = tid + p * 256;
            int slot = idx >> 4, cu = idx & 15;
            uint sid = (uint)ssrc[slot];
            uint4 v = hs1[(size_t)sid * 16 + cu];
            *(uint4*)((char*)Bs + ((idx * 16) ^ ((slot >> 3) << 4))) = v;
        }
        __syncthreads();
        // A fragment: segment indicator (bf16 1.0 where owner==row)
        uint2 ob = *(const uint2*)&sown[q * 8];
        union { uint u[4]; bf16x8 v; } au;
        #pragma unroll
        for (int pj = 0; pj < 4; ++pj) {
            uint bsrc = (pj < 2) ? ob.x : ob.y;
            uint sh = (uint)(pj & 1) * 16u;
            uint o0 = (bsrc >> sh) & 0xffu;
            uint o1 = (bsrc >> (sh + 8u)) & 0xffu;
            au.u[pj] = ((o0 == (uint)gl) ? 0x3f80u : 0u) |
                       ((o1 == (uint)gl) ? 0x3f800000u : 0u);
        }
        // B fragments from swizzled LDS (stride-256B u16 reads, <=2-way banks)
        union { u16 s[8]; bf16x8 v; } b0u, b1u;
        int sw = q << 4;
        #pragma unroll
        for (int j = 0; j < 8; ++j) {
            int k = q * 8 + j;
            b0u.s[j] = *(const u16*)((const char*)Bs + (((k * 128 + colb0) * 2) ^ sw));
            b1u.s[j] = *(const u16*)((const char*)Bs + (((k * 128 + colb1) * 2) ^ sw));
        }
        acc0 = __builtin_amdgcn_mfma_f32_16x16x32_bf16(au.v, b0u.v, acc0, 0, 0, 0);
        acc1 = __builtin_amdgcn_mfma_f32_16x16x32_bf16(au.v, b1u.v, acc1, 0, 0, 0);
        __syncthreads();
    }

    // scale rows by dis[n], pack bf16 into g tile
    #pragma unroll
    for (int reg = 0; reg < 4; ++reg) {
        int r = q * 4 + reg;
        int n = nb + r;
        float dn = (n < N) ? dis[n] : 0.f;
        gtu[r * 128 + colb0] = bf16r(acc0[reg] * dn);
        gtu[r * 128 + colb1] = bf16r(acc1[reg] * dn);
    }
    __syncthreads();

    // phase 2: HsHd = g @ Wc + brow
    uint* gtp = (uint*)gtu;
    bf16x8 afr[4];
    #pragma unroll
    for (int kk = 0; kk < 4; ++kk)
        afr[kk] = *(const bf16x8*)&gtp[gl * 64 + kk * 16 + q * 4];

    for (int cc = 0; cc < 4; ++cc) {
        int cC = wave * 4 + cc;
        f32x4 a2 = {0.f, 0.f, 0.f, 0.f};
        #pragma unroll
        for (int kk = 0; kk < 4; ++kk) {
            bf16x8 bfr = *(const bf16x8*)&Bf[(size_t)(cC * 4 + kk) * 64 + lane];
            a2 = __builtin_amdgcn_mfma_f32_16x16x32_bf16(afr[kk], bfr, a2, 0, 0, 0);
        }
        float bv = brow[cC * 16 + gl];
        #pragma unroll
        for (int reg = 0; reg < 4; ++reg) {
            int row = nb + q * 4 + reg;
            if (row < N)
                out[(size_t)row * 256 + cC * 16 + gl] = bf16r(a2[reg] + bv);
        }
    }
}

// ---------------- edge MLP: node-centric ----------------
// one 16-lane group per dst node: Hd row loaded+unpacked once; per edge gather
// Hs[src] + ear (coalesced), packed-fp32 MLP, DPP row reduction.
__launch_bounds__(256)
__global__ void edge_mlp_kernel(const uint4* __restrict__ HsHd,
                                const float4* __restrict__ ea,
                                const float4* __restrict__ ear, int use_ear,
                                const uint2* __restrict__ csr2,
                                const int* __restrict__ rowptr,
                                const float* __restrict__ Wb, const float* __restrict__ Wm2,
                                const float* __restrict__ bm2,
                                float* __restrict__ out, int N) {
    int lane = threadIdx.x & 63;
    int gl = lane & 15;

    f32x2 wb[4][4], w2[4];
    #pragma unroll
    for (int k = 0; k < 4; ++k) {
        const f32x2* wp = (const f32x2*)(Wb + k * HID + gl * 8);
        #pragma unroll
        for (int p = 0; p < 4; ++p) wb[k][p] = wp[p];
    }
    {
        const f32x2* wp = (const f32x2*)(Wm2 + gl * 8);
        #pragma unroll
        for (int p = 0; p < 4; ++p) w2[p] = wp[p];
    }
    float b2v = bm2[0];

    int n = (int)((blockIdx.x * 256u + threadIdx.x) >> 4);
    if (n >= N) return;
    int beg = rowptr[n], end = rowptr[n + 1];
    if (beg >= end) return;

    uint4 dvv = HsHd[(size_t)n * 32 + 16 + gl];
    f32x2 hd[4] = {bf2f(dvv.x), bf2f(dvv.y), bf2f(dvv.z), bf2f(dvv.w)};

    for (int base = beg; base < end; base += 4) {
        uint2 ce[4];
        uint4 hv[4];
        float4 eav[4];
        #pragma unroll
        for (int t = 0; t < 4; ++t) {
            int i = base + t;
            int j = (i < end) ? i : beg;
            ce[t] = csr2[j];
            hv[t] = HsHd[(size_t)((ce[t].x & 0xffffu) << 5) + gl];
            eav[t] = use_ear ? ear[j] : ea[ce[t].y];
        }
        float pr[4];
        #pragma unroll
        for (int t = 0; t < 4; ++t) {
            uint hu[4] = {hv[t].x, hv[t].y, hv[t].z, hv[t].w};
            f32x2 e0 = mk2(eav[t].x), e1 = mk2(eav[t].y);
            f32x2 e2 = mk2(eav[t].z), e3 = mk2(eav[t].w);
            f32x2 p2 = mk2(0.f);
            #pragma unroll
            for (int p = 0; p < 4; ++p) {
                f32x2 tt = pk_add2(bf2f(hu[p]), hd[p]);
                tt = pk_fma2(e0, wb[0][p], tt);
                tt = pk_fma2(e1, wb[1][p], tt);
                tt = pk_fma2(e2, wb[2][p], tt);
                tt = pk_fma2(e3, wb[3][p], tt);
                tt = max2z(tt);
                p2 = pk_fma2(tt, w2[p], p2);
            }
            pr[t] = p2.x + p2.y;
        }
        #pragma unroll
        for (int t = 0; t < 4; ++t) {
            float s = pr[t];
            s = dpp_add<0xB1>(s);
            s = dpp_add<0x4E>(s);
            s = dpp_add<0x124>(s);
            s = dpp_add<0x128>(s);
            pr[t] = s;
        }
        if (gl == 0) {
            #pragma unroll
            for (int t = 0; t < 4; ++t) {
                int i = base + t;
                if (i < end)
                    out[ce[t].y] = 1.f / (1.f + exp2f(-1.44269504f * (pr[t] + b2v)));
            }
        }
    }
}

// ---------------- launch ----------------

extern "C" void kernel_launch(void* const* d_in, const int* in_sizes, int n_in,
                              void* d_out, int out_size, void* d_ws, size_t ws_size,
                              hipStream_t stream) {
    const float* x    = (const float*)d_in[0];
    const float* ea   = (const float*)d_in[1];
    const float* W1   = (const float*)d_in[2];
    const float* b1   = (const float*)d_in[3];
    const float* W2   = (const float*)d_in[4];
    const float* b2   = (const float*)d_in[5];
    const float* Wm1  = (const float*)d_in[6];
    const float* bm1  = (const float*)d_in[7];
    const float* Wm2  = (const float*)d_in[8];
    const float* bm2  = (const float*)d_in[9];
    const int*   ei   = (const int*)d_in[10];

    const int N = in_sizes[0] / 5;
    const int E = in_sizes[1] / 4;
    const int* src = ei;
    const int* dst = ei + E;
    float* out = (float*)d_out;

    char* ws = (char*)d_ws;
    size_t off = 0;
    auto alloc = [&](size_t bytes) -> void* {
        void* p = ws + off;
        off = (off + bytes + 255) & ~(size_t)255;
        return p;
    };
    int*    cnt    = (int*)alloc((size_t)N * 4);
    int*    rowptr = (int*)alloc((size_t)(N + 1) * 4);
    int*    bsum   = (int*)alloc(256 * 4);
    float*  dis    = (float*)alloc((size_t)N * 4);
    int*    rank   = (int*)alloc((size_t)(E + 8) * 4);
    uint2*  csr2   = (uint2*)alloc((size_t)(E + 8) * 8);
    uint4*  xps    = (uint4*)alloc((size_t)N * 16);      // bf16 dis*x, 16 B rows
    uint*   hs1    = (uint*)alloc((size_t)N * 64 * 4);   // bf16 layer-1 features
    uint*   HsHd   = (uint*)alloc((size_t)N * 128 * 4);  // bf16 [N][256]
    uint*   fWc    = (uint*)alloc(16384 * 4);
    float*  brow   = (float*)alloc(256 * 4);
    float4* ear    = (float4*)alloc((size_t)(E + 8) * 16); // dst-sorted edge attrs
    int use_ear = (off <= ws_size) ? 1 : 0;
    (void)n_in; (void)out_size;

    const int NB = (N + 255) / 256;
    const int EB = (E + 255) / 256;

    // setup
    hipMemsetAsync(cnt, 0, (size_t)N * 4, stream);
    prep_kernel<<<260, 256, 0, stream>>>(W2, Wm1, b2, bm1, fWc, brow);
    hist_rank<<<EB, 256, 0, stream>>>(dst, cnt, rank, E);
    scan1<<<NB, 256, 0, stream>>>(cnt, rowptr, bsum, N);
    scan3x<<<NB, 256, 0, stream>>>(cnt, rowptr, bsum, dis, x, xps, N, E, NB);
    scatter2<<<EB, 256, 0, stream>>>(src, dst, rowptr, rank, (const float4*)ea,
                                     csr2, ear, use_ear, E);

    // layer 1 fused: hs1 = dis * relu((S·x)@W1 + b1), 4 lanes per node
    layer1_kernel<<<(N + 63) / 64, 256, 0, stream>>>(xps, csr2, rowptr, dis, W1, b1, hs1, N);

    // fused: g = S·h1 (indicator-MFMA segment-sum) ; HsHd = g @ Wc + brow
    agg_gemm<<<(N + 15) / 16, 256, 0, stream>>>((const uint4*)hs1, csr2, rowptr, dis,
                                                (const uint4*)fWc, brow,
                                                (unsigned short*)HsHd, N);

    // per-edge MLP + sigmoid, one 16-lane group per dst node
    edge_mlp_kernel<<<(N + 15) / 16, 256, 0, stream>>>((const uint4*)HsHd,
                                                       (const float4*)ea, (const float4*)ear,
                                                       use_ear, csr2, rowptr,
                                                       Wm1 + 256 * HID, Wm2, bm2, out, N);
}

// Round 3
// 249.525 us; speedup vs baseline: 1.0780x; 1.0780x over previous
//
#include <hip/hip_runtime.h>
#include <math.h>

#define HID 128
typedef unsigned int uint;
typedef unsigned short u16;
typedef __attribute__((ext_vector_type(8))) __bf16 bf16x8;
typedef __attribute__((ext_vector_type(4))) float f32x4;
typedef __attribute__((ext_vector_type(2))) float f32x2;

// ---------------- bf16 helpers (RNE) ----------------

__device__ __forceinline__ uint pack_bf2(float x, float y) {
    union { float f; uint u; } a, b;
    a.f = x; b.f = y;
    uint lo = (a.u + 0x7fffu + ((a.u >> 16) & 1u)) >> 16;
    uint hi = (b.u + 0x7fffu + ((b.u >> 16) & 1u)) & 0xffff0000u;
    return lo | hi;
}

__device__ __forceinline__ unsigned short bf16r(float x) {
    union { float f; uint u; } a; a.f = x;
    return (unsigned short)((a.u + 0x7fffu + ((a.u >> 16) & 1u)) >> 16);
}

__device__ __forceinline__ f32x2 bf2f(uint v) {
    union { uint u[2]; f32x2 f; } r;
    r.u[0] = v << 16;
    r.u[1] = v & 0xffff0000u;
    return r.f;
}

__device__ __forceinline__ f32x2 mk2(float s) { f32x2 r; r.x = s; r.y = s; return r; }
__device__ __forceinline__ f32x2 max2z(f32x2 a) {
    f32x2 r; r.x = fmaxf(a.x, 0.f); r.y = fmaxf(a.y, 0.f); return r;
}

// DPP-based add of a lane-permuted copy: single VALU op chain, no LDS pipe.
template<int CTRL>
__device__ __forceinline__ float dpp_add(float x) {
    union { float f; int i; } u, r;
    u.f = x;
    r.i = __builtin_amdgcn_update_dpp(0, u.i, CTRL, 0xf, 0xf, true);
    return x + r.f;
}

// ---------------- setup kernels ----------------

// composite weights: Wc = W2 @ [Wm1_top | Wm1_mid] (128 x 256), bf16 MFMA frag order
// brow = b2 @ [Wm1_top | Wm1_mid] + [bm1 | 0]  (256).  K-split x4 + DPP quad-reduce.
__global__ void prep_kernel(const float* __restrict__ W2, const float* __restrict__ Wm1,
                            const float* __restrict__ b2, const float* __restrict__ bm1,
                            uint* __restrict__ fWc, float* __restrict__ brow) {
    int t0 = blockIdx.x * blockDim.x + threadIdx.x;
    if (t0 < 65536) {       // 16384 outputs * 4 K-slices
        int ks = t0 & 3;
        int i = t0 >> 2;
        int p = i & 3, lane = (i >> 2) & 63, kk = (i >> 8) & 3, ct = i >> 10;
        int k = kk * 32 + (lane >> 4) * 8 + p * 2;
        int n2 = ct * 16 + (lane & 15);
        const float* wmc = (n2 < 128) ? (Wm1 + n2) : (Wm1 + 128 * HID + (n2 - 128));
        const float* w2r0 = W2 + (size_t)k * HID + ks * 32;
        const float* w2r1 = w2r0 + HID;
        const float* wm = wmc + (size_t)(ks * 32) * HID;
        float d0 = 0.f, d1 = 0.f;
        #pragma unroll 8
        for (int j = 0; j < 32; ++j) {
            float w = wm[(size_t)j * HID];
            d0 += w2r0[j] * w;
            d1 += w2r1[j] * w;
        }
        d0 = dpp_add<0xB1>(d0); d0 = dpp_add<0x4E>(d0);
        d1 = dpp_add<0xB1>(d1); d1 = dpp_add<0x4E>(d1);
        if (ks == 0) fWc[i] = pack_bf2(d0, d1);
    } else if (t0 < 65536 + 1024) {
        int r = t0 - 65536;
        int ks = r & 3;
        int i = r >> 2;
        const float* wmc = (i < 128) ? (Wm1 + i) : (Wm1 + 128 * HID + (i - 128));
        float d = 0.f;
        for (int j = ks * 32; j < ks * 32 + 32; ++j) d += b2[j] * wmc[(size_t)j * HID];
        d = dpp_add<0xB1>(d); d = dpp_add<0x4E>(d);
        if (ks == 0) brow[i] = d + ((i < 128) ? bm1[i] : 0.f);
    }
}

// histogram + within-bucket rank (atomic return value)
__global__ void hist_rank(const int* __restrict__ dst, int* __restrict__ cnt,
                          int* __restrict__ rank, int E) {
    int e = blockIdx.x * blockDim.x + threadIdx.x;
    if (e < E) rank[e] = atomicAdd(&cnt[dst[e]], 1);
}

__global__ void scan1(const int* __restrict__ cnt, int* __restrict__ excl,
                      int* __restrict__ bsum, int N) {
    __shared__ int sh[256];
    int tid = threadIdx.x;
    int gid = blockIdx.x * 256 + tid;
    int v = (gid < N) ? cnt[gid] : 0;
    sh[tid] = v;
    __syncthreads();
    for (int o = 1; o < 256; o <<= 1) {
        int t = (tid >= o) ? sh[tid - o] : 0;
        __syncthreads();
        sh[tid] += t;
        __syncthreads();
    }
    if (gid < N) excl[gid] = sh[tid] - v;
    if (tid == 255) bsum[blockIdx.x] = sh[255];
}

// finalize rowptr/dis + write xps[n] = bf16(dis[n]*x[n]) packed (5 dims + pad)
__global__ void scan3x(const int* __restrict__ cnt, int* __restrict__ rowptr,
                       const int* __restrict__ bsum,
                       float* __restrict__ dis, const float* __restrict__ x,
                       uint4* __restrict__ xps, int N, int E, int NB) {
    __shared__ int sh[256];
    __shared__ int ex[256];
    int tid = threadIdx.x;
    int v = (tid < NB) ? bsum[tid] : 0;
    sh[tid] = v;
    __syncthreads();
    for (int o = 1; o < 256; o <<= 1) {
        int t = (tid >= o) ? sh[tid - o] : 0;
        __syncthreads();
        sh[tid] += t;
        __syncthreads();
    }
    ex[tid] = sh[tid] - v;
    __syncthreads();
    int gid = blockIdx.x * 256 + tid;
    if (gid < N) {
        rowptr[gid] = rowptr[gid] + ex[blockIdx.x];
        float dn = rsqrtf((float)cnt[gid] + 1.0f);   // deg incl. self-loop
        dis[gid] = dn;
        const float* xr = x + (size_t)gid * 5;
        uint4 pk;
        pk.x = pack_bf2(dn * xr[0], dn * xr[1]);
        pk.y = pack_bf2(dn * xr[2], dn * xr[3]);
        pk.z = pack_bf2(dn * xr[4], 0.f);
        pk.w = 0u;
        xps[gid] = pk;
    }
    if (gid == N) rowptr[N] = E;
}

// atomic-free scatter: pos = rowptr[dst] + rank; csr2[pos] = (src|dst<<16, eid)
// also reorders ea into dst-sorted ear[] (so edge_mlp reads it coalesced);
// random stores are fire-and-forget, so the scatter side absorbs the latency cost.
__global__ void scatter2(const int* __restrict__ src, const int* __restrict__ dst,
                         const int* __restrict__ rowptr, const int* __restrict__ rank,
                         const float4* __restrict__ ea,
                         uint2* __restrict__ csr2, float4* __restrict__ ear,
                         int use_ear, int E) {
    int e = blockIdx.x * blockDim.x + threadIdx.x;
    if (e < E) {
        int d = dst[e];
        int pos = rowptr[d] + rank[e];
        csr2[pos] = make_uint2((uint)src[e] | ((uint)d << 16), (uint)e);
        if (use_ear) ear[pos] = ea[e];
    }
}

// ---------------- fused layer-1: hs1 = dis * relu( (S·x) @ W1 + b1 ) ----------------
// 4 lanes per node (quad): edge gathers split 4-way + DPP quad-reduce.
// Also zero-fills the sentinel row hs1[N] (used by agg_gemm's clamped slots).
__launch_bounds__(256)
__global__ void layer1_kernel(const uint4* __restrict__ xps, const uint2* __restrict__ csr2,
                              const int* __restrict__ rowptr, const float* __restrict__ dis,
                              const float* __restrict__ W1, const float* __restrict__ b1,
                              uint* __restrict__ hs1, int N) {
    __shared__ float sW[5 * HID];
    __shared__ float sb[HID];
    int tid = threadIdx.x;
    for (int i = tid; i < 5 * HID; i += 256) sW[i] = W1[i];
    for (int i = tid; i < HID; i += 256) sb[i] = b1[i];
    if (blockIdx.x == 0 && tid < 16) {
        uint4 z; z.x = 0u; z.y = 0u; z.z = 0u; z.w = 0u;
        ((uint4*)hs1)[(size_t)N * 16 + tid] = z;    // sentinel zero row
    }
    __syncthreads();

    int sub = tid & 3;
    int n = blockIdx.x * 64 + (tid >> 2);
    if (n >= N) return;
    int beg = rowptr[n], end = rowptr[n + 1];
    float a0 = 0.f, a1 = 0.f, a2 = 0.f, a3 = 0.f, a4 = 0.f;
    for (int i = beg + sub; i < end; i += 4) {
        uint s = csr2[i].x & 0xffffu;
        uint4 v = xps[s];
        f32x2 v01 = bf2f(v.x), v23 = bf2f(v.y), v4 = bf2f(v.z);
        a0 += v01.x; a1 += v01.y; a2 += v23.x; a3 += v23.y; a4 += v4.x;
    }
    a0 = dpp_add<0xB1>(a0); a0 = dpp_add<0x4E>(a0);
    a1 = dpp_add<0xB1>(a1); a1 = dpp_add<0x4E>(a1);
    a2 = dpp_add<0xB1>(a2); a2 = dpp_add<0x4E>(a2);
    a3 = dpp_add<0xB1>(a3); a3 = dpp_add<0x4E>(a3);
    a4 = dpp_add<0xB1>(a4); a4 = dpp_add<0x4E>(a4);
    {
        uint4 v = xps[n];   // self-loop term
        f32x2 v01 = bf2f(v.x), v23 = bf2f(v.y), v4 = bf2f(v.z);
        a0 += v01.x; a1 += v01.y; a2 += v23.x; a3 += v23.y; a4 += v4.x;
    }
    float dn = dis[n];
    a0 *= dn; a1 *= dn; a2 *= dn; a3 *= dn; a4 *= dn;   // sx row

    uint* op = hs1 + (size_t)n * 64;
    #pragma unroll
    for (int p = 0; p < 16; ++p) {
        int q = p * 4 + sub;
        int j = q * 2;
        float t0 = sb[j]     + a0 * sW[j]     + a1 * sW[HID + j]     + a2 * sW[2*HID + j]
                             + a3 * sW[3*HID + j] + a4 * sW[4*HID + j];
        float t1 = sb[j + 1] + a0 * sW[j + 1] + a1 * sW[HID + j + 1] + a2 * sW[2*HID + j + 1]
                             + a3 * sW[3*HID + j + 1] + a4 * sW[4*HID + j + 1];
        op[q] = pack_bf2(fmaxf(t0, 0.f) * dn, fmaxf(t1, 0.f) * dn);
    }
}

// ---------------- fused aggregate + GEMM ----------------
// block = 4 waves = 16 nodes.  Phase 1: one 16-lane group per node; each lane owns
// 8 columns (its uint4 slice) so aggregation has NO cross-lane ops, NO masks, NO
// barriers: 4-edge unrolled gather loop with csr2-index prefetch; out-of-range
// slots redirect to the zero sentinel row hs1[N] (one cndmask each).
// Phase 2: wave MFMAs the g tile against 4 of 16 column-tiles of Wc (+brow bias).
__launch_bounds__(256)
__global__ void agg_gemm(const uint4* __restrict__ hs1, const uint2* __restrict__ csr2,
                         const int* __restrict__ rowptr, const float* __restrict__ dis,
                         const uint4* __restrict__ Bf, const float* __restrict__ brow,
                         unsigned short* __restrict__ out, int N) {
    __shared__ uint gt[16][64];
    int tid = threadIdx.x;
    int wave = tid >> 6, lane = tid & 63;
    int gl = lane & 15, grp = lane >> 4;
    int nb = blockIdx.x * 16;
    int r = wave * 4 + grp;          // node slot 0..15 (group-per-node)
    int n = nb + r;
    const uint* cxp = (const uint*)csr2;   // stride-2 view of csr2[i].x

    f32x2 acc0 = mk2(0.f), acc1 = mk2(0.f), acc2 = mk2(0.f), acc3 = mk2(0.f);
    float dn = 0.f;
    if (n < N) {
        dn = dis[n];
        int beg = rowptr[n], end = rowptr[n + 1];
        int i = beg;
        if (i < end) {
            int lst = end - 1;
            uint cb[4];
            #pragma unroll
            for (int t = 0; t < 4; ++t) {
                int a = i + t; a = (a > lst) ? lst : a;
                cb[t] = cxp[(size_t)a * 2];
            }
            while (i < end) {
                uint s0 = (i     < end) ? (cb[0] & 0xffffu) : (uint)N;
                uint s1 = (i + 1 < end) ? (cb[1] & 0xffffu) : (uint)N;
                uint s2 = (i + 2 < end) ? (cb[2] & 0xffffu) : (uint)N;
                uint s3 = (i + 3 < end) ? (cb[3] & 0xffffu) : (uint)N;
                #pragma unroll
                for (int t = 0; t < 4; ++t) {           // prefetch next quad
                    int a = i + 4 + t; a = (a > lst) ? lst : a;
                    cb[t] = cxp[(size_t)a * 2];
                }
                uint4 v0 = hs1[(size_t)s0 * 16 + gl];
                uint4 v1 = hs1[(size_t)s1 * 16 + gl];
                uint4 v2 = hs1[(size_t)s2 * 16 + gl];
                uint4 v3 = hs1[(size_t)s3 * 16 + gl];
                acc0 += bf2f(v0.x); acc1 += bf2f(v0.y); acc2 += bf2f(v0.z); acc3 += bf2f(v0.w);
                acc0 += bf2f(v1.x); acc1 += bf2f(v1.y); acc2 += bf2f(v1.z); acc3 += bf2f(v1.w);
                acc0 += bf2f(v2.x); acc1 += bf2f(v2.y); acc2 += bf2f(v2.z); acc3 += bf2f(v2.w);
                acc0 += bf2f(v3.x); acc1 += bf2f(v3.y); acc2 += bf2f(v3.z); acc3 += bf2f(v3.w);
                i += 4;
            }
        }
        {   // self-loop row
            uint4 sv = hs1[(size_t)n * 16 + gl];
            acc0 += bf2f(sv.x); acc1 += bf2f(sv.y); acc2 += bf2f(sv.z); acc3 += bf2f(sv.w);
        }
    }
    // write g tile row (dn = 0 zeros out-of-range nodes)
    gt[r][gl * 4 + 0] = pack_bf2(acc0.x * dn, acc0.y * dn);
    gt[r][gl * 4 + 1] = pack_bf2(acc1.x * dn, acc1.y * dn);
    gt[r][gl * 4 + 2] = pack_bf2(acc2.x * dn, acc2.y * dn);
    gt[r][gl * 4 + 3] = pack_bf2(acc3.x * dn, acc3.y * dn);
    __syncthreads();

    // phase 2: HsHd = g @ Wc + brow
    int quad = lane >> 4;
    bf16x8 afr[4];
    #pragma unroll
    for (int kk = 0; kk < 4; ++kk)
        afr[kk] = *(const bf16x8*)&gt[gl][kk * 16 + quad * 4];

    for (int cc = 0; cc < 4; ++cc) {
        int c = wave * 4 + cc;
        f32x4 acc = {0.f, 0.f, 0.f, 0.f};
        #pragma unroll
        for (int kk = 0; kk < 4; ++kk) {
            bf16x8 bfr = *(const bf16x8*)&Bf[(size_t)(c * 4 + kk) * 64 + lane];
            acc = __builtin_amdgcn_mfma_f32_16x16x32_bf16(afr[kk], bfr, acc, 0, 0, 0);
        }
        float bv = brow[c * 16 + gl];
        #pragma unroll
        for (int reg = 0; reg < 4; ++reg) {
            int row = nb + quad * 4 + reg;
            if (row < N)
                out[(size_t)row * 256 + c * 16 + gl] = bf16r(acc[reg] + bv);
        }
    }
}

// edge-parallel edge MLP over dst-sorted csr2 (grid-stride form);
// 16-lane group takes 4 consecutive edges, 16 edges per wave per iteration.
// csr2 prefetch + DPP row reduction + coalesced ear edge attrs.
__launch_bounds__(256)
__global__ void edge_mlp_kernel(const uint4* __restrict__ HsHd,
                                const float4* __restrict__ ea,
                                const float4* __restrict__ ear, int use_ear,
                                const uint2* __restrict__ csr2,
                                const float* __restrict__ Wb, const float* __restrict__ Wm2,
                                const float* __restrict__ bm2,
                                float* __restrict__ out, int E) {
    int lane = threadIdx.x & 63;
    int gl = lane & 15, grp = lane >> 4;

    f32x2 wb[4][4], w2[4];
    #pragma unroll
    for (int k = 0; k < 4; ++k) {
        const f32x2* wp = (const f32x2*)(Wb + k * HID + gl * 8);
        #pragma unroll
        for (int p = 0; p < 4; ++p) wb[k][p] = wp[p];
    }
    {
        const f32x2* wp = (const f32x2*)(Wm2 + gl * 8);
        #pragma unroll
        for (int p = 0; p < 4; ++p) w2[p] = wp[p];
    }
    float b2v = bm2[0];

    int gwave = (blockIdx.x * blockDim.x + threadIdx.x) >> 6;
    int nw = (gridDim.x * blockDim.x) >> 6;
    int stride = nw * 16;
    int base = gwave * 16;
    if (base >= E) return;                       // wave-uniform

    uint2 ce[4];
    #pragma unroll
    for (int t = 0; t < 4; ++t) {
        int i = base + grp * 4 + t;
        ce[t] = csr2[(i < E) ? i : 0];
    }

    while (base < E) {
        int nbase = base + stride;

        // issue the long-latency gathers for the current batch
        uint4 hv[4], dv[4];
        float4 eav[4];
        uint eid[4];
        #pragma unroll
        for (int t = 0; t < 4; ++t) {
            uint cx = ce[t].x;
            eid[t] = ce[t].y;
            int i = base + grp * 4 + t;
            int j = (i < E) ? i : 0;
            hv[t] = HsHd[((cx & 0xffffu) << 5) + (uint)gl];
            dv[t] = HsHd[((cx >> 16) << 5) + 16u + (uint)gl];
            eav[t] = use_ear ? ear[j] : ea[eid[t]];
        }

        // prefetch next batch's csr2 (coalesced) while gathers are in flight
        if (nbase < E) {
            #pragma unroll
            for (int t = 0; t < 4; ++t) {
                int i = nbase + grp * 4 + t;
                ce[t] = csr2[(i < E) ? i : 0];
            }
        }

        float pr[4];
        #pragma unroll
        for (int t = 0; t < 4; ++t) {
            uint hu[4] = {hv[t].x, hv[t].y, hv[t].z, hv[t].w};
            uint du[4] = {dv[t].x, dv[t].y, dv[t].z, dv[t].w};
            f32x2 e0 = mk2(eav[t].x), e1 = mk2(eav[t].y);
            f32x2 e2 = mk2(eav[t].z), e3 = mk2(eav[t].w);
            f32x2 p2 = mk2(0.f);
            #pragma unroll
            for (int p = 0; p < 4; ++p) {
                f32x2 tt = bf2f(hu[p]) + bf2f(du[p]);
                tt += e0 * wb[0][p];
                tt += e1 * wb[1][p];
                tt += e2 * wb[2][p];
                tt += e3 * wb[3][p];
                tt = max2z(tt);
                p2 += tt * w2[p];
            }
            pr[t] = p2.x + p2.y;
        }
        // 16-lane row reduction via DPP adds (xor1, xor2, ror4, ror8)
        #pragma unroll
        for (int t = 0; t < 4; ++t) {
            float s = pr[t];
            s = dpp_add<0xB1>(s);
            s = dpp_add<0x4E>(s);
            s = dpp_add<0x124>(s);
            s = dpp_add<0x128>(s);
            pr[t] = s;
        }
        if (gl == 0) {
            #pragma unroll
            for (int t = 0; t < 4; ++t) {
                int i = base + grp * 4 + t;
                if (i < E)
                    out[eid[t]] = 1.f / (1.f + exp2f(-1.44269504f * (pr[t] + b2v)));
            }
        }
        base = nbase;
    }
}

// ---------------- launch ----------------

extern "C" void kernel_launch(void* const* d_in, const int* in_sizes, int n_in,
                              void* d_out, int out_size, void* d_ws, size_t ws_size,
                              hipStream_t stream) {
    const float* x    = (const float*)d_in[0];
    const float* ea   = (const float*)d_in[1];
    const float* W1   = (const float*)d_in[2];
    const float* b1   = (const float*)d_in[3];
    const float* W2   = (const float*)d_in[4];
    const float* b2   = (const float*)d_in[5];
    const float* Wm1  = (const float*)d_in[6];
    const float* bm1  = (const float*)d_in[7];
    const float* Wm2  = (const float*)d_in[8];
    const float* bm2  = (const float*)d_in[9];
    const int*   ei   = (const int*)d_in[10];

    const int N = in_sizes[0] / 5;
    const int E = in_sizes[1] / 4;
    const int* src = ei;
    const int* dst = ei + E;
    float* out = (float*)d_out;

    char* ws = (char*)d_ws;
    size_t off = 0;
    auto alloc = [&](size_t bytes) -> void* {
        void* p = ws + off;
        off = (off + bytes + 255) & ~(size_t)255;
        return p;
    };
    int*    cnt    = (int*)alloc((size_t)N * 4);
    int*    rowptr = (int*)alloc((size_t)(N + 1) * 4);
    int*    bsum   = (int*)alloc(256 * 4);
    float*  dis    = (float*)alloc((size_t)N * 4);
    int*    rank   = (int*)alloc((size_t)(E + 8) * 4);
    uint2*  csr2   = (uint2*)alloc((size_t)(E + 8) * 8);
    uint4*  xps    = (uint4*)alloc((size_t)N * 16);        // bf16 dis*x, 16 B rows
    uint*   hs1    = (uint*)alloc((size_t)(N + 1) * 64 * 4); // bf16 layer-1 + sentinel row
    uint*   HsHd   = (uint*)alloc((size_t)N * 128 * 4);    // bf16 [N][256]
    uint*   fWc    = (uint*)alloc(16384 * 4);
    float*  brow   = (float*)alloc(256 * 4);
    float4* ear    = (float4*)alloc((size_t)(E + 8) * 16); // dst-sorted edge attrs
    int use_ear = (off <= ws_size) ? 1 : 0;
    (void)n_in; (void)out_size;

    const int NB = (N + 255) / 256;
    const int EB = (E + 255) / 256;

    // setup
    hipMemsetAsync(cnt, 0, (size_t)N * 4, stream);
    prep_kernel<<<260, 256, 0, stream>>>(W2, Wm1, b2, bm1, fWc, brow);
    hist_rank<<<EB, 256, 0, stream>>>(dst, cnt, rank, E);
    scan1<<<NB, 256, 0, stream>>>(cnt, rowptr, bsum, N);
    scan3x<<<NB, 256, 0, stream>>>(cnt, rowptr, bsum, dis, x, xps, N, E, NB);
    scatter2<<<EB, 256, 0, stream>>>(src, dst, rowptr, rank, (const float4*)ea,
                                     csr2, ear, use_ear, E);

    // layer 1 fused: hs1 = dis * relu((S·x)@W1 + b1), 4 lanes per node
    layer1_kernel<<<(N + 63) / 64, 256, 0, stream>>>(xps, csr2, rowptr, dis, W1, b1, hs1, N);

    // fused: g = S·h1 (group-per-node, barrier-free) ; HsHd = g @ Wc + brow
    agg_gemm<<<(N + 15) / 16, 256, 0, stream>>>((const uint4*)hs1, csr2, rowptr, dis,
                                                (const uint4*)fWc, brow,
                                                (unsigned short*)HsHd, N);

    // per-edge MLP + sigmoid, dst-sorted order, grid-stride, coalesced ear
    edge_mlp_kernel<<<2048, 256, 0, stream>>>((const uint4*)HsHd,
                                              (const float4*)ea, (const float4*)ear,
                                              use_ear, csr2,
                                              Wm1 + 256 * HID, Wm2, bm2, out, E);
}